// Round 3
// baseline (231.003 us; speedup 1.0000x reference)
//
#include <hip/hip_runtime.h>
#include <hip/hip_bf16.h>
#include <math.h>

#define NB 16
#define RB 64
#define HB 128
#define WB 128
#define DB 256

typedef __attribute__((ext_vector_type(8))) short bf16x8;
typedef __attribute__((ext_vector_type(4))) float f32x4;
typedef __attribute__((ext_vector_type(2))) float f32x2;

static __device__ __forceinline__ short f2bf(float f) {
  __hip_bfloat16 h = __float2bfloat16(f);
  return *reinterpret_cast<short*>(&h);
}

// ws layout (floats):
//   ex_m [NB*RB*WB]  : exp(lx - mlx)                  (x-axis table, no scale)
//   ey_m [NB*RB*HB]  : exp(ly - mly) * s              (map normalization path)
//   (gap) [NB*RB*WB] : unused (kept for offset stability)
//   eyT  [NB*HB*RB]  : ey * s / (HB*WB)               (feat path, scales folded)

__global__ void tables_kernel(const float* __restrict__ roi,
                              float* __restrict__ ws,
                              float* __restrict__ out_params) {
  const int nr = blockIdx.x;            // n*64 + r
  const int n  = nr >> 6;
  const int r  = nr & 63;
  const int t  = threadIdx.x;           // 0..127

  const float mux = roi[nr * 4 + 0];
  const float muy = roi[nr * 4 + 1];
  const float sgx = roi[nr * 4 + 2];
  const float sgy = roi[nr * 4 + 3];

  const float g  = (t + 0.5f) * (1.0f / 128.0f);
  const float tx = fabsf(g - mux) / sgx;
  const float ty = fabsf(g - muy) / sgy;
  const float lx = -(tx * tx);          // BETA = 2.0
  const float ly = -(ty * ty);

  __shared__ float sdx[128], sdy[128];
  sdx[t] = lx; sdy[t] = ly;
  __syncthreads();
  for (int off = 64; off > 0; off >>= 1) {
    if (t < off) {
      sdx[t] = fmaxf(sdx[t], sdx[t + off]);
      sdy[t] = fmaxf(sdy[t], sdy[t + off]);
    }
    __syncthreads();
  }
  const float mlx = sdx[0], mly = sdy[0];

  const float em = expf(mlx + mly);             // == max over scores (separable)
  const float s  = em / (em + 1e-12f);
  const float exv = expf(lx - mlx);
  const float eyv = expf(ly - mly) * s;

  float* ex_m = ws;
  float* ey_m = ws + NB * RB * WB;
  float* eyT  = ws + 3 * NB * RB * WB;

  ex_m[nr * WB + t] = exv;
  ey_m[nr * HB + t] = eyv;
  eyT[(n * HB + t) * RB + r] = eyv * (1.0f / (HB * WB));

  if (t < 4) out_params[nr * 4 + t] = roi[nr * 4 + t];
}

__global__ void map_kernel(const float* __restrict__ ws,
                           float* __restrict__ out_map) {
  const float* ex_m = ws;
  const float* ey_m = ws + NB * RB * WB;
  const int total = NB * RB * HB * WB / 4;      // float4 count
  for (int idx = blockIdx.x * blockDim.x + threadIdx.x; idx < total;
       idx += gridDim.x * blockDim.x) {
    const int w4 = idx & 31;                    // 32 float4 per row
    const int h  = (idx >> 5) & 127;
    const int nr = idx >> 12;
    const float  ey = ey_m[nr * HB + h];
    const float4 ex = *reinterpret_cast<const float4*>(ex_m + nr * WB + w4 * 4);
    float4 o;
    o.x = ey * ex.x; o.y = ey * ex.y; o.z = ey * ex.z; o.w = ey * ex.w;
    reinterpret_cast<float4*>(out_map)[idx] = o;
  }
}

// MFMA feature kernel, v3: latency-oriented.
// Grid: 1024 blocks = (n:16) x (h-chunk:32, 4 rows) x (d-half:2).
// 256 threads = 4 waves; wave wv owns d in [dh*128 + wv*32, +32) -> acc[4][2],
// 32 VGPRs of accumulator, VGPR<=128 -> 4 waves/SIMD; 4 blocks/CU = 16 waves/CU.
// x loads are double-buffered 2 steps deep (xv[2][8], fully static indexing).
// A (roi map) is rank-1, built per step from L2-hot tables.
__global__ __launch_bounds__(256, 4) void feat_mfma_kernel(
    const float* __restrict__ x, const float* __restrict__ ws,
    float* __restrict__ out) {
  const float* ex_m = ws;                       // [NB*RB][WB]
  const float* eyT  = ws + 3 * NB * RB * WB;    // [NB*HB][RB]

  const int bid = blockIdx.x;
  const int n   = bid >> 6;
  const int hc  = (bid >> 1) & 31;
  const int dh  = bid & 1;
  const int h0  = hc * 4;
  const int t   = threadIdx.x;
  const int l   = t & 63;
  const int wv  = t >> 6;
  const int l15 = l & 15;
  const int lk  = (l >> 4) * 8;          // lane's k-offset within a k-step
  const int dbase = dh * 128 + wv * 32 + l15 * 2;

  f32x4 acc[4][2];
#pragma unroll
  for (int rf = 0; rf < 4; ++rf)
#pragma unroll
    for (int f = 0; f < 2; ++f) acc[rf][f] = (f32x4)0.0f;

  f32x2 xv[2][8];

  // prologue: prefetch step 0
  {
    const float* p = x + ((size_t)((n * HB + h0) * WB) + lk) * DB + dbase;
#pragma unroll
    for (int j = 0; j < 8; ++j)
      xv[0][j] = *reinterpret_cast<const f32x2*>(p + (size_t)j * DB);
  }

  float eyv[4];

#pragma unroll
  for (int s = 0; s < 16; ++s) {
    const int h  = h0 + (s >> 2);
    const int ks = s & 3;
    const int wl = ks * 32 + lk;

    // prefetch step s+1 (independent of this step's compute)
    if (s < 15) {
      const int hn  = h0 + ((s + 1) >> 2);
      const int ksn = (s + 1) & 3;
      const float* p =
          x + ((size_t)((n * HB + hn) * WB) + ksn * 32 + lk) * DB + dbase;
#pragma unroll
      for (int j = 0; j < 8; ++j)
        xv[(s + 1) & 1][j] = *reinterpret_cast<const f32x2*>(p + (size_t)j * DB);
    }

    if (ks == 0) {
#pragma unroll
      for (int rf = 0; rf < 4; ++rf)
        eyv[rf] = eyT[(n * HB + h) * RB + rf * 16 + l15];
    }

    // A fragments: rank-1 weights from L2-hot tables
    bf16x8 afr[4];
#pragma unroll
    for (int rf = 0; rf < 4; ++rf) {
      const float* exr = ex_m + (size_t)((n * RB + rf * 16 + l15) * WB) + wl;
      const f32x4 e0 = *reinterpret_cast<const f32x4*>(exr);
      const f32x4 e1 = *reinterpret_cast<const f32x4*>(exr + 4);
      bf16x8 a;
      a[0] = f2bf(eyv[rf] * e0.x); a[1] = f2bf(eyv[rf] * e0.y);
      a[2] = f2bf(eyv[rf] * e0.z); a[3] = f2bf(eyv[rf] * e0.w);
      a[4] = f2bf(eyv[rf] * e1.x); a[5] = f2bf(eyv[rf] * e1.y);
      a[6] = f2bf(eyv[rf] * e1.z); a[7] = f2bf(eyv[rf] * e1.w);
      afr[rf] = a;
    }

    // B fragments from the prefetched buffer (arrived during step s-1)
    bf16x8 bfr[2];
#pragma unroll
    for (int f = 0; f < 2; ++f) {
      bf16x8 b;
#pragma unroll
      for (int j = 0; j < 8; ++j) b[j] = f2bf(xv[s & 1][j][f]);
      bfr[f] = b;
    }

#pragma unroll
    for (int rf = 0; rf < 4; ++rf)
#pragma unroll
      for (int f = 0; f < 2; ++f)
        acc[rf][f] = __builtin_amdgcn_mfma_f32_16x16x32_bf16(
            afr[rf], bfr[f], acc[rf][f], 0, 0, 0);
  }

  // D layout: col = lane&15 (-> d), row = (lane>>4)*4 + reg (-> r). m89-verified.
#pragma unroll
  for (int rf = 0; rf < 4; ++rf) {
#pragma unroll
    for (int f = 0; f < 2; ++f) {
#pragma unroll
      for (int reg = 0; reg < 4; ++reg) {
        const int r = rf * 16 + (l >> 4) * 4 + reg;
        const int d = dbase + f;
        atomicAdd(out + (size_t)(n * RB + r) * DB + d, acc[rf][f][reg]);
      }
    }
  }
}

extern "C" void kernel_launch(void* const* d_in, const int* in_sizes, int n_in,
                              void* d_out, int out_size, void* d_ws, size_t ws_size,
                              hipStream_t stream) {
  const float* x   = (const float*)d_in[0];
  const float* roi = (const float*)d_in[1];
  float* out        = (float*)d_out;
  float* ws         = (float*)d_ws;      // 4 * 131072 floats = 2 MB
  float* out_feat   = out;                         // 16*64*256
  float* out_params = out + NB * RB * DB;          // 16*64*4
  float* out_map    = out_params + NB * RB * 4;    // 16*64*128*128

  // features accumulate via atomics -> zero every call (deterministic)
  hipMemsetAsync(out_feat, 0, (size_t)NB * RB * DB * sizeof(float), stream);

  tables_kernel<<<NB * RB, 128, 0, stream>>>(roi, ws, out_params);
  map_kernel<<<2048, 256, 0, stream>>>(ws, out_map);
  feat_mfma_kernel<<<1024, 256, 0, stream>>>(x, ws, out_feat);
}

// Round 4
// 206.539 us; speedup vs baseline: 1.1185x; 1.1185x over previous
//
#include <hip/hip_runtime.h>
#include <hip/hip_bf16.h>
#include <math.h>

#define NB 16
#define RB 64
#define HB 128
#define WB 128
#define DB 256
#define HW (HB * WB)

typedef __attribute__((ext_vector_type(8))) short bf16x8;
typedef __attribute__((ext_vector_type(4))) float f32x4;

static __device__ __forceinline__ short f2bf(float f) {
  __hip_bfloat16 h = __float2bfloat16(f);
  return *reinterpret_cast<short*>(&h);
}

// async global->LDS, 16B per lane, wave-uniform LDS base + lane*16 (HW semantics)
#define GLOAD_LDS16(gp, lp)                                          \
  __builtin_amdgcn_global_load_lds(                                  \
      (const __attribute__((address_space(1))) unsigned int*)(gp),   \
      (__attribute__((address_space(3))) unsigned int*)(lp), 16, 0, 0)

// ws layout (floats): ex_m [NB*RB*WB], ey_m [NB*RB*HB]
__global__ void tables_kernel(const float* __restrict__ roi,
                              float* __restrict__ ws,
                              float* __restrict__ out_params) {
  const int nr = blockIdx.x;            // n*64 + r
  const int t  = threadIdx.x;           // 0..127

  const float mux = roi[nr * 4 + 0];
  const float muy = roi[nr * 4 + 1];
  const float sgx = roi[nr * 4 + 2];
  const float sgy = roi[nr * 4 + 3];

  const float g  = (t + 0.5f) * (1.0f / 128.0f);
  const float tx = fabsf(g - mux) / sgx;
  const float ty = fabsf(g - muy) / sgy;
  const float lx = -(tx * tx);          // BETA = 2.0
  const float ly = -(ty * ty);

  __shared__ float sdx[128], sdy[128];
  sdx[t] = lx; sdy[t] = ly;
  __syncthreads();
  for (int off = 64; off > 0; off >>= 1) {
    if (t < off) {
      sdx[t] = fmaxf(sdx[t], sdx[t + off]);
      sdy[t] = fmaxf(sdy[t], sdy[t + off]);
    }
    __syncthreads();
  }
  const float mlx = sdx[0], mly = sdy[0];

  const float em = expf(mlx + mly);             // == max over scores (separable)
  const float s  = em / (em + 1e-12f);
  const float exv = expf(lx - mlx);
  const float eyv = expf(ly - mly) * s;

  float* ex_m = ws;
  float* ey_m = ws + NB * RB * WB;
  ex_m[nr * WB + t] = exv;
  ey_m[nr * HB + t] = eyv;

  if (t < 4) out_params[nr * 4 + t] = roi[nr * 4 + t];
}

__global__ void map_kernel(const float* __restrict__ ws,
                           float* __restrict__ out_map) {
  const float* ex_m = ws;
  const float* ey_m = ws + NB * RB * WB;
  const int total = NB * RB * HB * WB / 4;      // float4 count
  for (int idx = blockIdx.x * blockDim.x + threadIdx.x; idx < total;
       idx += gridDim.x * blockDim.x) {
    const int w4 = idx & 31;                    // 32 float4 per row
    const int h  = (idx >> 5) & 127;
    const int nr = idx >> 12;
    const float  ey = ey_m[nr * HB + h];
    const float4 ex = *reinterpret_cast<const float4*>(ex_m + nr * WB + w4 * 4);
    float4 o;
    o.x = ey * ex.x; o.y = ey * ex.y; o.z = ey * ex.z; o.w = ey * ex.w;
    reinterpret_cast<float4*>(out_map)[idx] = o;
  }
}

// feat v4: split-K LDS GEMM (m97-style staging).
// Grid: 512 = (n:16) x (kc:32, 512 contiguous pixels each).
// 256 threads = 4 waves; wave wv owns d in [wv*64, wv*64+64) via the
// interleave d = wv*64 + (l&15)*4 + f (verified in R2).
// Per K-step: 32 pixels staged in LDS (32 KB) via global_load_lds,
// double-buffered; A-fragments gathered from the f32 roi_map in d_out
// (lane-contiguous 32B, L2/L3-warm), cvt'd to bf16; 16 MFMA.
__global__ __launch_bounds__(256, 2) void feat_mfma_kernel(
    const float* __restrict__ x, const float* amap, float* outF) {
  __shared__ float buf[2][32 * DB];     // 2 x 32 KB

  const int bid = blockIdx.x;
  const int n   = bid >> 5;
  const int kc  = bid & 31;
  const int t   = threadIdx.x;
  const int l   = t & 63;
  const int wv  = t >> 6;
  const int l15 = l & 15;
  const int lk  = (l >> 4) * 8;         // lane's k-offset within a k-step

  const char* gx =
      (const char*)(x + ((size_t)n * HW + (size_t)kc * 512) * DB);

  f32x4 acc[4][4];
#pragma unroll
  for (int rf = 0; rf < 4; ++rf)
#pragma unroll
    for (int f = 0; f < 4; ++f) acc[rf][f] = (f32x4)0.0f;

  // prologue: stage buffer 0 (first 32 pixels of this chunk)
#pragma unroll
  for (int i = 0; i < 8; ++i)
    GLOAD_LDS16(gx + i * 4096 + wv * 1024 + l * 16,
                (char*)&buf[0][0] + i * 4096 + wv * 1024);
  __syncthreads();

#pragma unroll 2
  for (int bi = 0; bi < 16; ++bi) {
    const int cur = bi & 1;

    // stage next buffer (fire-and-forget; lands by the end-of-step barrier)
    if (bi < 15) {
      const char* gsrc = gx + (size_t)(bi + 1) * 32768;
#pragma unroll
      for (int i = 0; i < 8; ++i)
        GLOAD_LDS16(gsrc + i * 4096 + wv * 1024 + l * 16,
                    (char*)&buf[cur ^ 1][0] + i * 4096 + wv * 1024);
    }

    // A gathers: 2 x 16B contiguous per rf from the f32 map (row r, k-slice)
    const int k0 = kc * 512 + bi * 32;
    f32x4 a0[4], a1[4];
#pragma unroll
    for (int rf = 0; rf < 4; ++rf) {
      const float* ap = amap + (size_t)(n * RB + rf * 16 + l15) * HW + k0 + lk;
      a0[rf] = *reinterpret_cast<const f32x4*>(ap);
      a1[rf] = *reinterpret_cast<const f32x4*>(ap + 4);
    }

    // B from LDS: 8 x ds_read_b128
    f32x4 xv[8];
#pragma unroll
    for (int j = 0; j < 8; ++j)
      xv[j] = *reinterpret_cast<const f32x4*>(
          &buf[cur][(lk + j) * DB + wv * 64 + l15 * 4]);

    bf16x8 bfr[4];
#pragma unroll
    for (int f = 0; f < 4; ++f) {
      bf16x8 b;
#pragma unroll
      for (int j = 0; j < 8; ++j) b[j] = f2bf(xv[j][f]);
      bfr[f] = b;
    }
    bf16x8 afr[4];
#pragma unroll
    for (int rf = 0; rf < 4; ++rf) {
      bf16x8 a;
      a[0] = f2bf(a0[rf].x); a[1] = f2bf(a0[rf].y);
      a[2] = f2bf(a0[rf].z); a[3] = f2bf(a0[rf].w);
      a[4] = f2bf(a1[rf].x); a[5] = f2bf(a1[rf].y);
      a[6] = f2bf(a1[rf].z); a[7] = f2bf(a1[rf].w);
      afr[rf] = a;
    }

#pragma unroll
    for (int rf = 0; rf < 4; ++rf)
#pragma unroll
      for (int f = 0; f < 4; ++f)
        acc[rf][f] = __builtin_amdgcn_mfma_f32_16x16x32_bf16(
            afr[rf], bfr[f], acc[rf][f], 0, 0, 0);

    __syncthreads();   // drains vmcnt (stage landed) + lgkm; guards buffer reuse
  }

  // D layout: col = lane&15 (-> d), row = (lane>>4)*4 + reg (-> r). R2-verified.
  const float sc = 1.0f / (float)HW;
#pragma unroll
  for (int rf = 0; rf < 4; ++rf) {
#pragma unroll
    for (int f = 0; f < 4; ++f) {
#pragma unroll
      for (int reg = 0; reg < 4; ++reg) {
        const int r = rf * 16 + (l >> 4) * 4 + reg;
        const int d = wv * 64 + l15 * 4 + f;
        atomicAdd(outF + (size_t)(n * RB + r) * DB + d, acc[rf][f][reg] * sc);
      }
    }
  }
}

extern "C" void kernel_launch(void* const* d_in, const int* in_sizes, int n_in,
                              void* d_out, int out_size, void* d_ws, size_t ws_size,
                              hipStream_t stream) {
  const float* x   = (const float*)d_in[0];
  const float* roi = (const float*)d_in[1];
  float* out        = (float*)d_out;
  float* ws         = (float*)d_ws;      // 2 * 131072 floats = 1 MB
  float* out_feat   = out;                         // 16*64*256
  float* out_params = out + NB * RB * DB;          // 16*64*4
  float* out_map    = out_params + NB * RB * 4;    // 16*64*128*128

  // features accumulate via atomics -> zero every call (deterministic)
  hipMemsetAsync(out_feat, 0, (size_t)NB * RB * DB * sizeof(float), stream);

  tables_kernel<<<NB * RB, 128, 0, stream>>>(roi, ws, out_params);
  map_kernel<<<2048, 256, 0, stream>>>(ws, out_map);
  // feat reads the f32 map from d_out as its A operand (stream-ordered)
  feat_mfma_kernel<<<512, 256, 0, stream>>>(x, out_map, out_feat);
}

// Round 5
// 188.143 us; speedup vs baseline: 1.2278x; 1.0978x over previous
//
#include <hip/hip_runtime.h>
#include <hip/hip_bf16.h>
#include <math.h>

#define NB 16
#define RB 64
#define HB 128
#define WB 128
#define DB 256
#define HW (HB * WB)

typedef __attribute__((ext_vector_type(8))) short bf16x8;
typedef __attribute__((ext_vector_type(4))) float f32x4;

static __device__ __forceinline__ short f2bf(float f) {
  __hip_bfloat16 h = __float2bfloat16(f);
  return *reinterpret_cast<short*>(&h);
}

// async global->LDS, 16B per lane: HW writes wave-uniform LDS base + lane*16
#define GLOAD_LDS16(gp, lp)                                          \
  __builtin_amdgcn_global_load_lds(                                  \
      (const __attribute__((address_space(1))) unsigned int*)(gp),   \
      (__attribute__((address_space(3))) unsigned int*)(lp), 16, 0, 0)

// ws layout (floats): ex_m [NB*RB*WB], ey_m [NB*RB*HB]
__global__ void tables_kernel(const float* __restrict__ roi,
                              float* __restrict__ ws,
                              float* __restrict__ out_params) {
  const int nr = blockIdx.x;            // n*64 + r
  const int t  = threadIdx.x;           // 0..127

  const float mux = roi[nr * 4 + 0];
  const float muy = roi[nr * 4 + 1];
  const float sgx = roi[nr * 4 + 2];
  const float sgy = roi[nr * 4 + 3];

  const float g  = (t + 0.5f) * (1.0f / 128.0f);
  const float tx = fabsf(g - mux) / sgx;
  const float ty = fabsf(g - muy) / sgy;
  const float lx = -(tx * tx);          // BETA = 2.0
  const float ly = -(ty * ty);

  __shared__ float sdx[128], sdy[128];
  sdx[t] = lx; sdy[t] = ly;
  __syncthreads();
  for (int off = 64; off > 0; off >>= 1) {
    if (t < off) {
      sdx[t] = fmaxf(sdx[t], sdx[t + off]);
      sdy[t] = fmaxf(sdy[t], sdy[t + off]);
    }
    __syncthreads();
  }
  const float mlx = sdx[0], mly = sdy[0];

  const float em = expf(mlx + mly);             // == max over scores (separable)
  const float s  = em / (em + 1e-12f);
  const float exv = expf(lx - mlx);
  const float eyv = expf(ly - mly) * s;

  float* ex_m = ws;
  float* ey_m = ws + NB * RB * WB;
  ex_m[nr * WB + t] = exv;
  ey_m[nr * HB + t] = eyv;

  if (t < 4) out_params[nr * 4 + t] = roi[nr * 4 + t];
}

__global__ void map_kernel(const float* __restrict__ ws,
                           float* __restrict__ out_map) {
  const float* ex_m = ws;
  const float* ey_m = ws + NB * RB * WB;
  const int total = NB * RB * HB * WB / 4;      // float4 count
  for (int idx = blockIdx.x * blockDim.x + threadIdx.x; idx < total;
       idx += gridDim.x * blockDim.x) {
    const int w4 = idx & 31;                    // 32 float4 per row
    const int h  = (idx >> 5) & 127;
    const int nr = idx >> 12;
    const float  ey = ey_m[nr * HB + h];
    const float4 ex = *reinterpret_cast<const float4*>(ex_m + nr * WB + w4 * 4);
    float4 o;
    o.x = ey * ex.x; o.y = ey * ex.y; o.z = ey * ex.z; o.w = ey * ex.w;
    reinterpret_cast<float4*>(out_map)[idx] = o;
  }
}

// feat v5: counted-vmcnt pipelined split-K GEMM (T3+T4).
// Grid: 512 = (n:16) x (kc:32, 512 contiguous px = 4 h-rows each).
// 4 LDS buffers x 32 KB (depth-3 prefetch). All table data in registers,
// vmcnt(0)-drained BEFORE staging starts -> loop vmcnt counts staging only.
// Per step: wait vmcnt(16) [own buffer landed] -> s_barrier -> sched_barrier
// -> stage buffer i+3 -> ds_read + rank-1 A build + 16 MFMA. Fully unrolled.
__global__ __launch_bounds__(256, 1) void feat_mfma_kernel(
    const float* __restrict__ x, const float* __restrict__ ws, float* outF) {
  __shared__ float buf[4][32 * DB];     // 128 KB

  const float* ex_m = ws;
  const float* ey_m = ws + NB * RB * WB;

  const int bid = blockIdx.x;
  const int n   = bid >> 5;
  const int kc  = bid & 31;
  const int t   = threadIdx.x;
  const int l   = t & 63;
  const int wv  = t >> 6;
  const int l15 = l & 15;
  const int lk  = (l >> 4) * 8;         // lane's k-offset within a k-step
  const int h0  = kc * 4;               // first h-row of this chunk

  const char* gx =
      (const char*)(x + ((size_t)n * HW + (size_t)kc * 512) * DB);
  char* lbase = (char*)&buf[0][0];

  // ---- prologue 1: table values into registers, drained before staging ----
  f32x4 exr[4][4][2];                   // [rf][ks][half]
  float eyv[4][4];                      // [hh][rf]
#pragma unroll
  for (int rf = 0; rf < 4; ++rf) {
    const float* exrow = ex_m + (size_t)(n * RB + rf * 16 + l15) * WB;
#pragma unroll
    for (int ks = 0; ks < 4; ++ks) {
      exr[rf][ks][0] = *reinterpret_cast<const f32x4*>(exrow + ks * 32 + lk);
      exr[rf][ks][1] = *reinterpret_cast<const f32x4*>(exrow + ks * 32 + lk + 4);
    }
  }
#pragma unroll
  for (int hh = 0; hh < 4; ++hh)
#pragma unroll
    for (int rf = 0; rf < 4; ++rf)
      eyv[hh][rf] = ey_m[(size_t)(n * RB + rf * 16 + l15) * HB + h0 + hh];
  asm volatile("s_waitcnt vmcnt(0)" ::: "memory");  // tables resolved; vmcnt now tracks staging only

  f32x4 acc[4][4];
#pragma unroll
  for (int rf = 0; rf < 4; ++rf)
#pragma unroll
    for (int f = 0; f < 4; ++f) acc[rf][f] = (f32x4)0.0f;

#define STAGE(bi, slot) do {                                                 \
    const char* gsrc_ = gx + (size_t)(bi) * 32768;                           \
    char* ldst_ = lbase + (slot) * 32768;                                    \
    _Pragma("unroll")                                                        \
    for (int ii = 0; ii < 8; ++ii)                                           \
      GLOAD_LDS16(gsrc_ + ii * 4096 + wv * 1024 + l * 16,                    \
                  ldst_ + ii * 4096 + wv * 1024);                            \
  } while (0)

  // ---- prologue 2: stage buffers 0,1,2 (24 loads in flight per wave) ----
  STAGE(0, 0); STAGE(1, 1); STAGE(2, 2);

#define KSTEP(bi, VM, DO_STAGE) do {                                         \
    asm volatile("s_waitcnt vmcnt(" #VM ")" ::: "memory");                   \
    __builtin_amdgcn_s_barrier();                                            \
    __builtin_amdgcn_sched_barrier(0);                                       \
    if (DO_STAGE) STAGE((bi) + 3, ((bi) + 3) & 3);                           \
    const float* bp_ = &buf[(bi) & 3][0];                                    \
    f32x4 xv_[8];                                                            \
    _Pragma("unroll")                                                        \
    for (int j = 0; j < 8; ++j)                                              \
      xv_[j] = *reinterpret_cast<const f32x4*>(                              \
          bp_ + (lk + j) * DB + wv * 64 + l15 * 4);                          \
    bf16x8 bfr_[4];                                                          \
    _Pragma("unroll")                                                        \
    for (int f = 0; f < 4; ++f) {                                            \
      bf16x8 b_;                                                             \
      _Pragma("unroll")                                                      \
      for (int j = 0; j < 8; ++j) b_[j] = f2bf(xv_[j][f]);                   \
      bfr_[f] = b_;                                                          \
    }                                                                        \
    bf16x8 afr_[4];                                                          \
    _Pragma("unroll")                                                        \
    for (int rf = 0; rf < 4; ++rf) {                                         \
      const float ey_ = eyv[(bi) >> 2][rf];                                  \
      const f32x4 e0_ = exr[rf][(bi) & 3][0];                                \
      const f32x4 e1_ = exr[rf][(bi) & 3][1];                                \
      bf16x8 a_;                                                             \
      a_[0] = f2bf(ey_ * e0_.x); a_[1] = f2bf(ey_ * e0_.y);                  \
      a_[2] = f2bf(ey_ * e0_.z); a_[3] = f2bf(ey_ * e0_.w);                  \
      a_[4] = f2bf(ey_ * e1_.x); a_[5] = f2bf(ey_ * e1_.y);                  \
      a_[6] = f2bf(ey_ * e1_.z); a_[7] = f2bf(ey_ * e1_.w);                  \
      afr_[rf] = a_;                                                         \
    }                                                                        \
    _Pragma("unroll")                                                        \
    for (int rf = 0; rf < 4; ++rf)                                           \
      _Pragma("unroll")                                                      \
      for (int f = 0; f < 4; ++f)                                            \
        acc[rf][f] = __builtin_amdgcn_mfma_f32_16x16x32_bf16(                \
            afr_[rf], bfr_[f], acc[rf][f], 0, 0, 0);                         \
  } while (0)

  KSTEP(0, 16, 1);  KSTEP(1, 16, 1);  KSTEP(2, 16, 1);  KSTEP(3, 16, 1);
  KSTEP(4, 16, 1);  KSTEP(5, 16, 1);  KSTEP(6, 16, 1);  KSTEP(7, 16, 1);
  KSTEP(8, 16, 1);  KSTEP(9, 16, 1);  KSTEP(10, 16, 1); KSTEP(11, 16, 1);
  KSTEP(12, 16, 1); KSTEP(13, 16, 0); KSTEP(14, 8, 0);  KSTEP(15, 0, 0);

#undef KSTEP
#undef STAGE

  // D layout: col = lane&15 (-> d), row = (lane>>4)*4 + reg (-> r). R2/R4-verified.
  const float sc = 1.0f / (float)HW;
#pragma unroll
  for (int rf = 0; rf < 4; ++rf) {
#pragma unroll
    for (int f = 0; f < 4; ++f) {
#pragma unroll
      for (int reg = 0; reg < 4; ++reg) {
        const int r = rf * 16 + (l >> 4) * 4 + reg;
        const int d = wv * 64 + l15 * 4 + f;
        atomicAdd(outF + (size_t)(n * RB + r) * DB + d, acc[rf][f][reg] * sc);
      }
    }
  }
}

extern "C" void kernel_launch(void* const* d_in, const int* in_sizes, int n_in,
                              void* d_out, int out_size, void* d_ws, size_t ws_size,
                              hipStream_t stream) {
  const float* x   = (const float*)d_in[0];
  const float* roi = (const float*)d_in[1];
  float* out        = (float*)d_out;
  float* ws         = (float*)d_ws;      // 2 * 131072 floats = 1 MB
  float* out_feat   = out;                         // 16*64*256
  float* out_params = out + NB * RB * DB;          // 16*64*4
  float* out_map    = out_params + NB * RB * 4;    // 16*64*128*128

  // features accumulate via atomics -> zero every call (deterministic)
  hipMemsetAsync(out_feat, 0, (size_t)NB * RB * DB * sizeof(float), stream);

  tables_kernel<<<NB * RB, 128, 0, stream>>>(roi, ws, out_params);
  feat_mfma_kernel<<<512, 256, 0, stream>>>(x, ws, out_feat);
  map_kernel<<<2048, 256, 0, stream>>>(ws, out_map);
}